// Round 17
// baseline (125.858 us; speedup 1.0000x reference)
//
#include <hip/hip_runtime.h>

// SelfAttention (SAGAN-style), MI355X — bf16 MFMA implementation, v17.
// Math: out[b,c,n] = gamma * sum_m [exp(S[m,n]) / Z[m]] * V[b,c,m] + x[b,c,n]
//   S[m,n] = sum_q Q[q,m] K[q,n],  Z[m] = sum_j exp(S[m,j]).
// exp2 trick: Q pre-scaled by log2(e); L[m] = -log2(Z[m]) folded into the
// S-MFMA accumulator init => P = exp2(S' + L) with zero extra VALU.
//
// v17 (R16 post-mortem): SL=16 regressed (119.8 -> 125.2; PO traffic
// doubled, no latency-hiding gain — V-staging already covers it). The SL
// derivative is negative above 8, so probe SL=4 (PO halves to 8 MB,
// combine reads halve). Launcher-only change from v15. If neutral or
// worse, v15 (SL=8, 119.8 µs) is final.
// Failure clusters (do not reintroduce): 512-thread attn (v6/v7);
// dense [n][8] Q/K + quad-predicated frag loads (v11); fat per-wave
// register prefetch in attn (v10); Q/L LDS staging in attn (v14/attn_v9).

constexpr int Bn = 4, Cc = 64, Q8 = 8, Np = 4096;
constexpr int QK_STR = 32;  // padded q dim (shorts) per position
constexpr int PSTR = 40;    // attn Plds row stride in shorts (80B, 16B-aligned)
constexpr int VSTR = 32;    // attn Vlds row stride in shorts (64B; lane*16B linear)
constexpr int NSL = 8;      // zsum n-slices
constexpr int XSTR = 72;    // qkv xT row stride in shorts (144B, 16B-aligned)

typedef float f32x4 __attribute__((ext_vector_type(4)));
typedef short short8 __attribute__((ext_vector_type(8)));

__device__ inline unsigned int f2bf(float x) {  // RNE f32->bf16 (as u16)
    unsigned int u = __float_as_uint(x);
    u += 0x7fff + ((u >> 16) & 1);
    return u >> 16;
}
__device__ inline float bf2f(unsigned int u) { return __uint_as_float(u << 16); }

__device__ inline unsigned cvt_pk_bf16(float a, float b) {  // lo=bf16(a), hi=bf16(b)
    unsigned r;
    asm("v_cvt_pk_bf16_f32 %0, %1, %2" : "=v"(r) : "v"(a), "v"(b));
    return r;
}
__device__ inline float exp2g(float x) {
#if __has_builtin(__builtin_amdgcn_exp2f)
    return __builtin_amdgcn_exp2f(x);
#else
    return exp2f(x);
#endif
}
__device__ inline float log2g(float x) {
#if __has_builtin(__builtin_amdgcn_logf)
    return __builtin_amdgcn_logf(x);
#else
    return log2f(x);
#endif
}

// ---------------- kernel 1: QKV projections via MFMA (padded Q/K output) ----------------
__global__ __launch_bounds__(64) void qkv_mfma(
    const float* __restrict__ x,
    const float* __restrict__ Wq, const float* __restrict__ bq,
    const float* __restrict__ Wk, const float* __restrict__ bk,
    const float* __restrict__ Wv, const float* __restrict__ bv,
    unsigned short* __restrict__ Qp, unsigned short* __restrict__ Kp,
    unsigned short* __restrict__ Vb)
{
    __shared__ unsigned short xT[64 * XSTR];  // [n_local][c] bf16
    const int lane = threadIdx.x;
    const int quad = lane >> 4, l15 = lane & 15;
    const int gpos = blockIdx.x * 64;        // over Bn*Np
    const int ot = blockIdx.y;               // 0..4
    const int b = gpos >> 12, n0 = gpos & (Np - 1);
    const float LOG2E = 1.4426950408889634f;

    {
        const float* xrow = x + (size_t)(b * Cc + lane) * Np + n0;
        #pragma unroll
        for (int i4 = 0; i4 < 16; i4++) {
            float4 v = *(const float4*)&xrow[i4 * 4];
            int nb4 = i4 * 4;
            xT[(nb4 + 0) * XSTR + lane] = (unsigned short)f2bf(v.x);
            xT[(nb4 + 1) * XSTR + lane] = (unsigned short)f2bf(v.y);
            xT[(nb4 + 2) * XSTR + lane] = (unsigned short)f2bf(v.z);
            xT[(nb4 + 3) * XSTR + lane] = (unsigned short)f2bf(v.w);
        }
    }
    __syncthreads();

    const float* Wrow;
    if (ot == 0) Wrow = (l15 < 8) ? (Wq + l15 * Cc) : (Wk + (l15 - 8) * Cc);
    else         Wrow = Wv + ((ot - 1) * 16 + l15) * Cc;
    short8 wa[2];
    #pragma unroll
    for (int kf = 0; kf < 2; kf++) {
        #pragma unroll
        for (int jj = 0; jj < 8; jj++)
            wa[kf][jj] = (short)f2bf(Wrow[kf * 32 + quad * 8 + jj]);
    }
    float bias[4];
    if (ot == 0) {
        const float* bb = (quad < 2) ? bq : bk;
        int off = (quad & 1) * 4;
        #pragma unroll
        for (int r = 0; r < 4; r++) bias[r] = bb[off + r];
    } else {
        #pragma unroll
        for (int r = 0; r < 4; r++) bias[r] = bv[(ot - 1) * 16 + quad * 4 + r];
    }

    #pragma unroll
    for (int nt = 0; nt < 4; nt++) {
        short8 xb0 = *(const short8*)&xT[(nt * 16 + l15) * XSTR + quad * 8];
        short8 xb1 = *(const short8*)&xT[(nt * 16 + l15) * XSTR + 32 + quad * 8];
        f32x4 cc = __builtin_amdgcn_mfma_f32_16x16x32_bf16(
            wa[0], xb0, f32x4{0.f, 0.f, 0.f, 0.f}, 0, 0, 0);
        cc = __builtin_amdgcn_mfma_f32_16x16x32_bf16(wa[1], xb1, cc, 0, 0, 0);
        int n = n0 + nt * 16 + l15;
        if (ot == 0) {
            float v0 = cc[0] + bias[0], v1 = cc[1] + bias[1];
            float v2 = cc[2] + bias[2], v3 = cc[3] + bias[3];
            if (quad < 2) { v0 *= LOG2E; v1 *= LOG2E; v2 *= LOG2E; v3 *= LOG2E; }
            unsigned p01 = cvt_pk_bf16(v0, v1), p23 = cvt_pk_bf16(v2, v3);
            unsigned short* rowp = (quad < 2 ? Qp : Kp)
                + ((size_t)(b * Np + n)) * QK_STR;
            *(uint2*)(rowp + (quad & 1) * 4) = make_uint2(p01, p23);
            if ((quad & 1) == 0) {
                *(uint4*)(rowp + 8) = make_uint4(0, 0, 0, 0);
            } else {
                *(uint4*)(rowp + 16) = make_uint4(0, 0, 0, 0);
                *(uint4*)(rowp + 24) = make_uint4(0, 0, 0, 0);
            }
        } else {
            #pragma unroll
            for (int r = 0; r < 4; r++) {
                int vr = (ot - 1) * 16 + quad * 4 + r;
                Vb[(size_t)(b * Cc + vr) * Np + n] =
                    (unsigned short)f2bf(cc[r] + bias[r]);
            }
        }
    }
}

// ---------------- kernel 2: Z partials via MFMA, 2 m-tiles/wave ----------------
__global__ __launch_bounds__(256) void zsum_v6(
    const unsigned short* __restrict__ Qp, const unsigned short* __restrict__ Kp,
    float* __restrict__ ZP)
{
    const int tid = threadIdx.x, w = tid >> 6, lane = tid & 63;
    const int quad = lane >> 4, l15 = lane & 15;
    const int bz = blockIdx.z, ns = blockIdx.y;
    const int m0 = blockIdx.x * 128 + w * 32;

    short8 qa0 = *(const short8*)
        &Qp[((size_t)(bz * Np + m0 + l15)) * QK_STR + quad * 8];
    short8 qa1 = *(const short8*)
        &Qp[((size_t)(bz * Np + m0 + 16 + l15)) * QK_STR + quad * 8];
    const unsigned short* kbase = Kp + (size_t)bz * Np * QK_STR;
    const int nbase = ns * (Np / NSL);

    float z0 = 0.f, z1 = 0.f, z2 = 0.f, z3 = 0.f;
    float z4 = 0.f, z5 = 0.f, z6 = 0.f, z7 = 0.f;
    #pragma unroll 4
    for (int nt = 0; nt < Np / NSL; nt += 16) {
        short8 kb = *(const short8*)
            &kbase[(size_t)(nbase + nt + l15) * QK_STR + quad * 8];
        f32x4 s0 = __builtin_amdgcn_mfma_f32_16x16x32_bf16(
            qa0, kb, f32x4{0.f, 0.f, 0.f, 0.f}, 0, 0, 0);
        f32x4 s1 = __builtin_amdgcn_mfma_f32_16x16x32_bf16(
            qa1, kb, f32x4{0.f, 0.f, 0.f, 0.f}, 0, 0, 0);
        z0 += exp2g(s0[0]); z1 += exp2g(s0[1]);
        z2 += exp2g(s0[2]); z3 += exp2g(s0[3]);
        z4 += exp2g(s1[0]); z5 += exp2g(s1[1]);
        z6 += exp2g(s1[2]); z7 += exp2g(s1[3]);
    }
    #pragma unroll
    for (int mask = 1; mask < 16; mask <<= 1) {
        z0 += __shfl_xor(z0, mask); z1 += __shfl_xor(z1, mask);
        z2 += __shfl_xor(z2, mask); z3 += __shfl_xor(z3, mask);
        z4 += __shfl_xor(z4, mask); z5 += __shfl_xor(z5, mask);
        z6 += __shfl_xor(z6, mask); z7 += __shfl_xor(z7, mask);
    }
    if (l15 == 0) {
        float* zp = &ZP[((size_t)(bz * NSL + ns)) * Np + m0];
        *(float4*)&zp[quad * 4] = make_float4(z0, z1, z2, z3);
        *(float4*)&zp[16 + quad * 4] = make_float4(z4, z5, z6, z7);
    }
}

// ---------------- kernel 3: L[m] = -log2(Z[m]) ----------------
__global__ __launch_bounds__(256) void zred(
    const float* __restrict__ ZP, float* __restrict__ Lg)
{
    int i = blockIdx.x * 256 + threadIdx.x;  // over Bn*Np
    int b = i >> 12, m = i & (Np - 1);
    float z = 0.f;
    #pragma unroll
    for (int s = 0; s < NSL; s++) z += ZP[((size_t)(b * NSL + s)) * Np + m];
    Lg[(size_t)b * Np + m] = -log2g(z);
}

// ---------------- kernel 4: out partials via MFMA, LDS-staged V (v13 verbatim) ----------------
__global__ __launch_bounds__(256) void attn_v8(
    const unsigned short* __restrict__ Qp, const unsigned short* __restrict__ Kp,
    const unsigned short* __restrict__ Vb, const float* __restrict__ Lg,
    unsigned short* __restrict__ PO, int Ms, int SL)
{
    __shared__ unsigned short Plds[128 * PSTR];     // [n_local][m_local]
    __shared__ unsigned short Vlds[2][64 * VSTR];   // [c][m_local 0..31]
    const int tid = threadIdx.x, w = tid >> 6, lane = tid & 63;
    const int quad = lane >> 4, l15 = lane & 15;
    const int bz = blockIdx.z, by = blockIdx.y, nb = blockIdx.x * 128;

    // staging role: thread t covers V row c = t>>2, m-chunk = t&3 (8 shorts)
    const int sc = tid >> 2, sch = tid & 3;
    const unsigned short* vsrc = Vb + (size_t)(bz * Cc + sc) * Np + sch * 8;

    short8 kf[2];
    #pragma unroll
    for (int t = 0; t < 2; t++) {
        int n = nb + (2 * w + t) * 16 + l15;
        kf[t] = *(const short8*)&Kp[((size_t)(bz * Np + n)) * QK_STR + quad * 8];
    }
    f32x4 acc[4][2];
    #pragma unroll
    for (int ct = 0; ct < 4; ct++)
        #pragma unroll
        for (int t = 0; t < 2; t++) acc[ct][t] = f32x4{0.f, 0.f, 0.f, 0.f};

    const int m_base = by * Ms;

    // prologue: tile 0 -> buf 0
    {
        uint4 p0 = *(const uint4*)&vsrc[m_base];
        *(uint4*)&Vlds[0][sc * VSTR + sch * 8] = p0;
    }

    for (int mi = 0; mi < Ms; mi += 32) {
        const int m0 = m_base + mi;
        const int cur = (mi >> 5) & 1;
        // prefetch next V tile into registers (wrap: harmless on last iter)
        const int mn = m_base + ((mi + 32) & (Ms - 1));
        uint4 pfN = *(const uint4*)&vsrc[mn];

        __syncthreads();  // publishes buf[cur]; fences reuse of buf[cur^1]

        // phase 1: P[m0..m0+31][wave's 32 n] = exp2(S' + L[m]), bf16, into LDS
        #pragma unroll
        for (int mt = 0; mt < 2; mt++) {
            short8 qa = *(const short8*)
                &Qp[((size_t)(bz * Np + m0 + mt * 16 + l15)) * QK_STR + quad * 8];
            f32x4 Lc = *(const f32x4*)
                &Lg[(size_t)bz * Np + m0 + mt * 16 + quad * 4];
            #pragma unroll
            for (int t = 0; t < 2; t++) {
                f32x4 s = __builtin_amdgcn_mfma_f32_16x16x32_bf16(qa, kf[t], Lc, 0, 0, 0);
                unsigned p01 = cvt_pk_bf16(exp2g(s[0]), exp2g(s[1]));
                unsigned p23 = cvt_pk_bf16(exp2g(s[2]), exp2g(s[3]));
                int nl = (2 * w + t) * 16 + l15;
                *(uint2*)&Plds[nl * PSTR + mt * 16 + quad * 4] = make_uint2(p01, p23);
            }
        }
        // phase 2: acc[c, n] += V[c, m0..31] * P[m0..31, n]
        short8 pb[2];
        #pragma unroll
        for (int t = 0; t < 2; t++)
            pb[t] = *(const short8*)&Plds[(w * 32 + t * 16 + l15) * PSTR + quad * 8];
        #pragma unroll
        for (int ct = 0; ct < 4; ct++) {
            short8 ua = *(const short8*)&Vlds[cur][(ct * 16 + l15) * VSTR + quad * 8];
            #pragma unroll
            for (int t = 0; t < 2; t++)
                acc[ct][t] = __builtin_amdgcn_mfma_f32_16x16x32_bf16(
                    ua, pb[t], acc[ct][t], 0, 0, 0);
        }
        // publish next tile into the other buffer (fenced by next barrier)
        *(uint4*)&Vlds[cur ^ 1][sc * VSTR + sch * 8] = pfN;
    }
    unsigned short* po = PO + ((size_t)((bz * SL + by) * Cc)) * Np + nb;
    #pragma unroll
    for (int ct = 0; ct < 4; ct++)
        #pragma unroll
        for (int t = 0; t < 2; t++) {
            int c = ct * 16 + quad * 4, n = w * 32 + t * 16 + l15;
            #pragma unroll
            for (int r = 0; r < 4; r++)
                po[(size_t)(c + r) * Np + n] = (unsigned short)f2bf(acc[ct][t][r]);
        }
}

// ---------------- kernel 5: combine slices + gamma*out + x (8-wide) ----------------
__global__ __launch_bounds__(256) void combine_kernel(
    const unsigned short* __restrict__ PO, const float* __restrict__ x,
    const float* __restrict__ gamma, float* __restrict__ out, int sl2)
{
    int idx8 = (blockIdx.x * 256 + threadIdx.x) * 8;  // over Bn*Cc*Np
    int b = idx8 >> 18;
    int c = (idx8 >> 12) & 63;
    int n = idx8 & (Np - 1);
    float o[8];
    #pragma unroll
    for (int i = 0; i < 8; i++) o[i] = 0.f;
    for (int sl = 0; sl < sl2; ++sl) {
        uint4 u = *(const uint4*)&PO[(size_t)((b * sl2 + sl) * Cc + c) * Np + n];
        o[0] += bf2f(u.x & 0xffff); o[1] += bf2f(u.x >> 16);
        o[2] += bf2f(u.y & 0xffff); o[3] += bf2f(u.y >> 16);
        o[4] += bf2f(u.z & 0xffff); o[5] += bf2f(u.z >> 16);
        o[6] += bf2f(u.w & 0xffff); o[7] += bf2f(u.w >> 16);
    }
    float g = gamma[0];
    float4 x0 = *(const float4*)&x[idx8];
    float4 x1 = *(const float4*)&x[idx8 + 4];
    float4 r0 = make_float4(g * o[0] + x0.x, g * o[1] + x0.y,
                            g * o[2] + x0.z, g * o[3] + x0.w);
    float4 r1 = make_float4(g * o[4] + x1.x, g * o[5] + x1.y,
                            g * o[6] + x1.z, g * o[7] + x1.w);
    *(float4*)&out[idx8] = r0;
    *(float4*)&out[idx8 + 4] = r1;
}

extern "C" void kernel_launch(void* const* d_in, const int* in_sizes, int n_in,
                              void* d_out, int out_size, void* d_ws, size_t ws_size,
                              hipStream_t stream)
{
    const float* x     = (const float*)d_in[0];
    const float* Wq    = (const float*)d_in[1];
    const float* bq    = (const float*)d_in[2];
    const float* Wk    = (const float*)d_in[3];
    const float* bk    = (const float*)d_in[4];
    const float* Wv    = (const float*)d_in[5];
    const float* bv    = (const float*)d_in[6];
    const float* gamma = (const float*)d_in[7];
    float* out = (float*)d_out;

    unsigned short* Qp = (unsigned short*)d_ws;               // 1 MB (padded [n][32])
    unsigned short* Kp = Qp + (size_t)Bn * Np * QK_STR;       // 1 MB
    unsigned short* Vb = Kp + (size_t)Bn * Np * QK_STR;       // 2 MB (bf16 V)
    float* Lg   = (float*)(Vb + (size_t)Bn * Cc * Np);        // 64 KB: -log2(Z)
    float* ZP   = Lg + (size_t)Bn * Np;                       // NSL partials, 512 KB
    unsigned short* PO = (unsigned short*)(ZP + (size_t)Bn * NSL * Np);  // SL * 2 MB

    size_t baseB = (size_t)Bn * Np * QK_STR * 2 * 2 + (size_t)Bn * Cc * Np * 2
                 + (size_t)Bn * Np * 4 + (size_t)Bn * NSL * Np * 4;
    int SL = 4;  // m-slices for attn partials (512 blocks; probing below SL=8)
    while (SL > 1 && baseB + (size_t)Bn * SL * Cc * Np * 2 > ws_size) SL >>= 1;

    qkv_mfma<<<dim3(Bn * Np / 64, 5), 64, 0, stream>>>(x, Wq, bq, Wk, bk, Wv, bv,
                                                       Qp, Kp, Vb);
    zsum_v6<<<dim3(Np / 128, NSL, Bn), 256, 0, stream>>>(Qp, Kp, ZP);
    zred<<<Bn * Np / 256, 256, 0, stream>>>(ZP, Lg);
    attn_v8<<<dim3(Np / 128, SL, Bn), 256, 0, stream>>>(Qp, Kp, Vb, Lg,
                                                        PO, Np / SL, SL);
    combine_kernel<<<Bn * Cc * Np / (256 * 8), 256, 0, stream>>>(PO, x, gamma, out, SL);
}

// Round 18
// 119.576 us; speedup vs baseline: 1.0525x; 1.0525x over previous
//
#include <hip/hip_runtime.h>

// SelfAttention (SAGAN-style), MI355X — bf16 MFMA implementation, v18 == v15.
// FINAL CONFIGURATION: measured-best (119.8 µs, R15). SL sweep complete:
// 4 -> 125.9, 8 -> 119.8 (optimum), 16 -> 125.2.
//
// Math: out[b,c,n] = gamma * sum_m [exp(S[m,n]) / Z[m]] * V[b,c,m] + x[b,c,n]
//   S[m,n] = sum_q Q[q,m] K[q,n],  Z[m] = sum_j exp(S[m,j]).
// exp2 trick: Q pre-scaled by log2(e); L[m] = -log2(Z[m]) folded into the
// S-MFMA accumulator init => P = exp2(S' + L) with zero extra VALU.
//
// Optimization history (measured): fp32 scalar 783 -> bf16 MFMA 228 ->
// occupancy fixes 147 -> MFMA qkv + LDS-V-staged attn 121 -> zsum 2-tiles
// 119.8. Failure clusters (do not reintroduce): 512-thread attn (v6/v7);
// dense [n][8] Q/K + quad-predicated frag loads (v11); fat per-wave
// register prefetch in attn (v10); Q/L LDS staging in attn (v14/attn_v9).

constexpr int Bn = 4, Cc = 64, Q8 = 8, Np = 4096;
constexpr int QK_STR = 32;  // padded q dim (shorts) per position
constexpr int PSTR = 40;    // attn Plds row stride in shorts (80B, 16B-aligned)
constexpr int VSTR = 32;    // attn Vlds row stride in shorts (64B; lane*16B linear)
constexpr int NSL = 8;      // zsum n-slices
constexpr int XSTR = 72;    // qkv xT row stride in shorts (144B, 16B-aligned)

typedef float f32x4 __attribute__((ext_vector_type(4)));
typedef short short8 __attribute__((ext_vector_type(8)));

__device__ inline unsigned int f2bf(float x) {  // RNE f32->bf16 (as u16)
    unsigned int u = __float_as_uint(x);
    u += 0x7fff + ((u >> 16) & 1);
    return u >> 16;
}
__device__ inline float bf2f(unsigned int u) { return __uint_as_float(u << 16); }

__device__ inline unsigned cvt_pk_bf16(float a, float b) {  // lo=bf16(a), hi=bf16(b)
    unsigned r;
    asm("v_cvt_pk_bf16_f32 %0, %1, %2" : "=v"(r) : "v"(a), "v"(b));
    return r;
}
__device__ inline float exp2g(float x) {
#if __has_builtin(__builtin_amdgcn_exp2f)
    return __builtin_amdgcn_exp2f(x);
#else
    return exp2f(x);
#endif
}
__device__ inline float log2g(float x) {
#if __has_builtin(__builtin_amdgcn_logf)
    return __builtin_amdgcn_logf(x);
#else
    return log2f(x);
#endif
}

// ---------------- kernel 1: QKV projections via MFMA (padded Q/K output) ----------------
__global__ __launch_bounds__(64) void qkv_mfma(
    const float* __restrict__ x,
    const float* __restrict__ Wq, const float* __restrict__ bq,
    const float* __restrict__ Wk, const float* __restrict__ bk,
    const float* __restrict__ Wv, const float* __restrict__ bv,
    unsigned short* __restrict__ Qp, unsigned short* __restrict__ Kp,
    unsigned short* __restrict__ Vb)
{
    __shared__ unsigned short xT[64 * XSTR];  // [n_local][c] bf16
    const int lane = threadIdx.x;
    const int quad = lane >> 4, l15 = lane & 15;
    const int gpos = blockIdx.x * 64;        // over Bn*Np
    const int ot = blockIdx.y;               // 0..4
    const int b = gpos >> 12, n0 = gpos & (Np - 1);
    const float LOG2E = 1.4426950408889634f;

    {
        const float* xrow = x + (size_t)(b * Cc + lane) * Np + n0;
        #pragma unroll
        for (int i4 = 0; i4 < 16; i4++) {
            float4 v = *(const float4*)&xrow[i4 * 4];
            int nb4 = i4 * 4;
            xT[(nb4 + 0) * XSTR + lane] = (unsigned short)f2bf(v.x);
            xT[(nb4 + 1) * XSTR + lane] = (unsigned short)f2bf(v.y);
            xT[(nb4 + 2) * XSTR + lane] = (unsigned short)f2bf(v.z);
            xT[(nb4 + 3) * XSTR + lane] = (unsigned short)f2bf(v.w);
        }
    }
    __syncthreads();

    const float* Wrow;
    if (ot == 0) Wrow = (l15 < 8) ? (Wq + l15 * Cc) : (Wk + (l15 - 8) * Cc);
    else         Wrow = Wv + ((ot - 1) * 16 + l15) * Cc;
    short8 wa[2];
    #pragma unroll
    for (int kf = 0; kf < 2; kf++) {
        #pragma unroll
        for (int jj = 0; jj < 8; jj++)
            wa[kf][jj] = (short)f2bf(Wrow[kf * 32 + quad * 8 + jj]);
    }
    float bias[4];
    if (ot == 0) {
        const float* bb = (quad < 2) ? bq : bk;
        int off = (quad & 1) * 4;
        #pragma unroll
        for (int r = 0; r < 4; r++) bias[r] = bb[off + r];
    } else {
        #pragma unroll
        for (int r = 0; r < 4; r++) bias[r] = bv[(ot - 1) * 16 + quad * 4 + r];
    }

    #pragma unroll
    for (int nt = 0; nt < 4; nt++) {
        short8 xb0 = *(const short8*)&xT[(nt * 16 + l15) * XSTR + quad * 8];
        short8 xb1 = *(const short8*)&xT[(nt * 16 + l15) * XSTR + 32 + quad * 8];
        f32x4 cc = __builtin_amdgcn_mfma_f32_16x16x32_bf16(
            wa[0], xb0, f32x4{0.f, 0.f, 0.f, 0.f}, 0, 0, 0);
        cc = __builtin_amdgcn_mfma_f32_16x16x32_bf16(wa[1], xb1, cc, 0, 0, 0);
        int n = n0 + nt * 16 + l15;
        if (ot == 0) {
            float v0 = cc[0] + bias[0], v1 = cc[1] + bias[1];
            float v2 = cc[2] + bias[2], v3 = cc[3] + bias[3];
            if (quad < 2) { v0 *= LOG2E; v1 *= LOG2E; v2 *= LOG2E; v3 *= LOG2E; }
            unsigned p01 = cvt_pk_bf16(v0, v1), p23 = cvt_pk_bf16(v2, v3);
            unsigned short* rowp = (quad < 2 ? Qp : Kp)
                + ((size_t)(b * Np + n)) * QK_STR;
            *(uint2*)(rowp + (quad & 1) * 4) = make_uint2(p01, p23);
            if ((quad & 1) == 0) {
                *(uint4*)(rowp + 8) = make_uint4(0, 0, 0, 0);
            } else {
                *(uint4*)(rowp + 16) = make_uint4(0, 0, 0, 0);
                *(uint4*)(rowp + 24) = make_uint4(0, 0, 0, 0);
            }
        } else {
            #pragma unroll
            for (int r = 0; r < 4; r++) {
                int vr = (ot - 1) * 16 + quad * 4 + r;
                Vb[(size_t)(b * Cc + vr) * Np + n] =
                    (unsigned short)f2bf(cc[r] + bias[r]);
            }
        }
    }
}

// ---------------- kernel 2: Z partials via MFMA, 2 m-tiles/wave ----------------
__global__ __launch_bounds__(256) void zsum_v6(
    const unsigned short* __restrict__ Qp, const unsigned short* __restrict__ Kp,
    float* __restrict__ ZP)
{
    const int tid = threadIdx.x, w = tid >> 6, lane = tid & 63;
    const int quad = lane >> 4, l15 = lane & 15;
    const int bz = blockIdx.z, ns = blockIdx.y;
    const int m0 = blockIdx.x * 128 + w * 32;

    short8 qa0 = *(const short8*)
        &Qp[((size_t)(bz * Np + m0 + l15)) * QK_STR + quad * 8];
    short8 qa1 = *(const short8*)
        &Qp[((size_t)(bz * Np + m0 + 16 + l15)) * QK_STR + quad * 8];
    const unsigned short* kbase = Kp + (size_t)bz * Np * QK_STR;
    const int nbase = ns * (Np / NSL);

    float z0 = 0.f, z1 = 0.f, z2 = 0.f, z3 = 0.f;
    float z4 = 0.f, z5 = 0.f, z6 = 0.f, z7 = 0.f;
    #pragma unroll 4
    for (int nt = 0; nt < Np / NSL; nt += 16) {
        short8 kb = *(const short8*)
            &kbase[(size_t)(nbase + nt + l15) * QK_STR + quad * 8];
        f32x4 s0 = __builtin_amdgcn_mfma_f32_16x16x32_bf16(
            qa0, kb, f32x4{0.f, 0.f, 0.f, 0.f}, 0, 0, 0);
        f32x4 s1 = __builtin_amdgcn_mfma_f32_16x16x32_bf16(
            qa1, kb, f32x4{0.f, 0.f, 0.f, 0.f}, 0, 0, 0);
        z0 += exp2g(s0[0]); z1 += exp2g(s0[1]);
        z2 += exp2g(s0[2]); z3 += exp2g(s0[3]);
        z4 += exp2g(s1[0]); z5 += exp2g(s1[1]);
        z6 += exp2g(s1[2]); z7 += exp2g(s1[3]);
    }
    #pragma unroll
    for (int mask = 1; mask < 16; mask <<= 1) {
        z0 += __shfl_xor(z0, mask); z1 += __shfl_xor(z1, mask);
        z2 += __shfl_xor(z2, mask); z3 += __shfl_xor(z3, mask);
        z4 += __shfl_xor(z4, mask); z5 += __shfl_xor(z5, mask);
        z6 += __shfl_xor(z6, mask); z7 += __shfl_xor(z7, mask);
    }
    if (l15 == 0) {
        float* zp = &ZP[((size_t)(bz * NSL + ns)) * Np + m0];
        *(float4*)&zp[quad * 4] = make_float4(z0, z1, z2, z3);
        *(float4*)&zp[16 + quad * 4] = make_float4(z4, z5, z6, z7);
    }
}

// ---------------- kernel 3: L[m] = -log2(Z[m]) ----------------
__global__ __launch_bounds__(256) void zred(
    const float* __restrict__ ZP, float* __restrict__ Lg)
{
    int i = blockIdx.x * 256 + threadIdx.x;  // over Bn*Np
    int b = i >> 12, m = i & (Np - 1);
    float z = 0.f;
    #pragma unroll
    for (int s = 0; s < NSL; s++) z += ZP[((size_t)(b * NSL + s)) * Np + m];
    Lg[(size_t)b * Np + m] = -log2g(z);
}

// ---------------- kernel 4: out partials via MFMA, LDS-staged V ----------------
__global__ __launch_bounds__(256) void attn_v8(
    const unsigned short* __restrict__ Qp, const unsigned short* __restrict__ Kp,
    const unsigned short* __restrict__ Vb, const float* __restrict__ Lg,
    unsigned short* __restrict__ PO, int Ms, int SL)
{
    __shared__ unsigned short Plds[128 * PSTR];     // [n_local][m_local]
    __shared__ unsigned short Vlds[2][64 * VSTR];   // [c][m_local 0..31]
    const int tid = threadIdx.x, w = tid >> 6, lane = tid & 63;
    const int quad = lane >> 4, l15 = lane & 15;
    const int bz = blockIdx.z, by = blockIdx.y, nb = blockIdx.x * 128;

    // staging role: thread t covers V row c = t>>2, m-chunk = t&3 (8 shorts)
    const int sc = tid >> 2, sch = tid & 3;
    const unsigned short* vsrc = Vb + (size_t)(bz * Cc + sc) * Np + sch * 8;

    short8 kf[2];
    #pragma unroll
    for (int t = 0; t < 2; t++) {
        int n = nb + (2 * w + t) * 16 + l15;
        kf[t] = *(const short8*)&Kp[((size_t)(bz * Np + n)) * QK_STR + quad * 8];
    }
    f32x4 acc[4][2];
    #pragma unroll
    for (int ct = 0; ct < 4; ct++)
        #pragma unroll
        for (int t = 0; t < 2; t++) acc[ct][t] = f32x4{0.f, 0.f, 0.f, 0.f};

    const int m_base = by * Ms;

    // prologue: tile 0 -> buf 0
    {
        uint4 p0 = *(const uint4*)&vsrc[m_base];
        *(uint4*)&Vlds[0][sc * VSTR + sch * 8] = p0;
    }

    for (int mi = 0; mi < Ms; mi += 32) {
        const int m0 = m_base + mi;
        const int cur = (mi >> 5) & 1;
        // prefetch next V tile into registers (wrap: harmless on last iter)
        const int mn = m_base + ((mi + 32) & (Ms - 1));
        uint4 pfN = *(const uint4*)&vsrc[mn];

        __syncthreads();  // publishes buf[cur]; fences reuse of buf[cur^1]

        // phase 1: P[m0..m0+31][wave's 32 n] = exp2(S' + L[m]), bf16, into LDS
        #pragma unroll
        for (int mt = 0; mt < 2; mt++) {
            short8 qa = *(const short8*)
                &Qp[((size_t)(bz * Np + m0 + mt * 16 + l15)) * QK_STR + quad * 8];
            f32x4 Lc = *(const f32x4*)
                &Lg[(size_t)bz * Np + m0 + mt * 16 + quad * 4];
            #pragma unroll
            for (int t = 0; t < 2; t++) {
                f32x4 s = __builtin_amdgcn_mfma_f32_16x16x32_bf16(qa, kf[t], Lc, 0, 0, 0);
                unsigned p01 = cvt_pk_bf16(exp2g(s[0]), exp2g(s[1]));
                unsigned p23 = cvt_pk_bf16(exp2g(s[2]), exp2g(s[3]));
                int nl = (2 * w + t) * 16 + l15;
                *(uint2*)&Plds[nl * PSTR + mt * 16 + quad * 4] = make_uint2(p01, p23);
            }
        }
        // phase 2: acc[c, n] += V[c, m0..31] * P[m0..31, n]
        short8 pb[2];
        #pragma unroll
        for (int t = 0; t < 2; t++)
            pb[t] = *(const short8*)&Plds[(w * 32 + t * 16 + l15) * PSTR + quad * 8];
        #pragma unroll
        for (int ct = 0; ct < 4; ct++) {
            short8 ua = *(const short8*)&Vlds[cur][(ct * 16 + l15) * VSTR + quad * 8];
            #pragma unroll
            for (int t = 0; t < 2; t++)
                acc[ct][t] = __builtin_amdgcn_mfma_f32_16x16x32_bf16(
                    ua, pb[t], acc[ct][t], 0, 0, 0);
        }
        // publish next tile into the other buffer (fenced by next barrier)
        *(uint4*)&Vlds[cur ^ 1][sc * VSTR + sch * 8] = pfN;
    }
    unsigned short* po = PO + ((size_t)((bz * SL + by) * Cc)) * Np + nb;
    #pragma unroll
    for (int ct = 0; ct < 4; ct++)
        #pragma unroll
        for (int t = 0; t < 2; t++) {
            int c = ct * 16 + quad * 4, n = w * 32 + t * 16 + l15;
            #pragma unroll
            for (int r = 0; r < 4; r++)
                po[(size_t)(c + r) * Np + n] = (unsigned short)f2bf(acc[ct][t][r]);
        }
}

// ---------------- kernel 5: combine slices + gamma*out + x (8-wide) ----------------
__global__ __launch_bounds__(256) void combine_kernel(
    const unsigned short* __restrict__ PO, const float* __restrict__ x,
    const float* __restrict__ gamma, float* __restrict__ out, int sl2)
{
    int idx8 = (blockIdx.x * 256 + threadIdx.x) * 8;  // over Bn*Cc*Np
    int b = idx8 >> 18;
    int c = (idx8 >> 12) & 63;
    int n = idx8 & (Np - 1);
    float o[8];
    #pragma unroll
    for (int i = 0; i < 8; i++) o[i] = 0.f;
    for (int sl = 0; sl < sl2; ++sl) {
        uint4 u = *(const uint4*)&PO[(size_t)((b * sl2 + sl) * Cc + c) * Np + n];
        o[0] += bf2f(u.x & 0xffff); o[1] += bf2f(u.x >> 16);
        o[2] += bf2f(u.y & 0xffff); o[3] += bf2f(u.y >> 16);
        o[4] += bf2f(u.z & 0xffff); o[5] += bf2f(u.z >> 16);
        o[6] += bf2f(u.w & 0xffff); o[7] += bf2f(u.w >> 16);
    }
    float g = gamma[0];
    float4 x0 = *(const float4*)&x[idx8];
    float4 x1 = *(const float4*)&x[idx8 + 4];
    float4 r0 = make_float4(g * o[0] + x0.x, g * o[1] + x0.y,
                            g * o[2] + x0.z, g * o[3] + x0.w);
    float4 r1 = make_float4(g * o[4] + x1.x, g * o[5] + x1.y,
                            g * o[6] + x1.z, g * o[7] + x1.w);
    *(float4*)&out[idx8] = r0;
    *(float4*)&out[idx8 + 4] = r1;
}

extern "C" void kernel_launch(void* const* d_in, const int* in_sizes, int n_in,
                              void* d_out, int out_size, void* d_ws, size_t ws_size,
                              hipStream_t stream)
{
    const float* x     = (const float*)d_in[0];
    const float* Wq    = (const float*)d_in[1];
    const float* bq    = (const float*)d_in[2];
    const float* Wk    = (const float*)d_in[3];
    const float* bk    = (const float*)d_in[4];
    const float* Wv    = (const float*)d_in[5];
    const float* bv    = (const float*)d_in[6];
    const float* gamma = (const float*)d_in[7];
    float* out = (float*)d_out;

    unsigned short* Qp = (unsigned short*)d_ws;               // 1 MB (padded [n][32])
    unsigned short* Kp = Qp + (size_t)Bn * Np * QK_STR;       // 1 MB
    unsigned short* Vb = Kp + (size_t)Bn * Np * QK_STR;       // 2 MB (bf16 V)
    float* Lg   = (float*)(Vb + (size_t)Bn * Cc * Np);        // 64 KB: -log2(Z)
    float* ZP   = Lg + (size_t)Bn * Np;                       // NSL partials, 512 KB
    unsigned short* PO = (unsigned short*)(ZP + (size_t)Bn * NSL * Np);  // SL * 2 MB

    size_t baseB = (size_t)Bn * Np * QK_STR * 2 * 2 + (size_t)Bn * Cc * Np * 2
                 + (size_t)Bn * Np * 4 + (size_t)Bn * NSL * Np * 4;
    int SL = 8;  // m-slices for attn partials — measured optimum (4/8/16 swept)
    while (SL > 1 && baseB + (size_t)Bn * SL * Cc * Np * 2 > ws_size) SL >>= 1;

    qkv_mfma<<<dim3(Bn * Np / 64, 5), 64, 0, stream>>>(x, Wq, bq, Wk, bk, Wv, bv,
                                                       Qp, Kp, Vb);
    zsum_v6<<<dim3(Np / 128, NSL, Bn), 256, 0, stream>>>(Qp, Kp, ZP);
    zred<<<Bn * Np / 256, 256, 0, stream>>>(ZP, Lg);
    attn_v8<<<dim3(Np / 128, SL, Bn), 256, 0, stream>>>(Qp, Kp, Vb, Lg,
                                                        PO, Np / SL, SL);
    combine_kernel<<<Bn * Cc * Np / (256 * 8), 256, 0, stream>>>(PO, x, gamma, out, SL);
}